// Round 1
// baseline (251.214 us; speedup 1.0000x reference)
//
#include <hip/hip_runtime.h>

// BlockSparseFlashAttention — Phi-3-small blocksparse prefill, MI355X (gfx950)
// S=2048, H=32, HKV=8 (GQA x4), D=128, BLK=64, LOCAL=16, VERT=8, HEAD_SLIDE=1
//
// Design notes (R1):
//  - bf16 MFMA (16x16x32) flash attention; fp32 in/out, bf16 compute
//    (harness threshold 6.875e-2 is bf16-scaled).
//  - WG = 256 thr = 4 waves, covers 128 query rows (2 query blocks) -> grid 512.
//    Wave owns 32 rows: Q frags in registers, K/V frag reads amortized x2.
//  - S^T = K * Q^T so query dim sits on lane&15: softmax state is scalar/lane,
//    reductions are in-lane + shfl_xor(16,32); O^T = V^T * P^T gives float4 stores.
//  - LDS: Ks[64][136] row-major, Vt[128][72] transposed V, Pt[wave][32][72] P
//    row-major. All strides 16B-multiples (b128-aligned), bank-balanced.

typedef __bf16 bf16_t;
typedef __bf16 bf16x4 __attribute__((ext_vector_type(4)));
typedef __bf16 bf16x8 __attribute__((ext_vector_type(8)));
typedef float  fx4    __attribute__((ext_vector_type(4)));

#define SCALE_F 0.08838834764831845f
#define LOG2E_F 1.4426950408889634f

__launch_bounds__(256, 2)
__global__ void bsfa_kernel(const float* __restrict__ Q,
                            const float* __restrict__ K,
                            const float* __restrict__ V,
                            float* __restrict__ O)
{
    const int sb   = blockIdx.x;      // 0..15 : 128-row query superblock
    const int h    = blockIdx.y;      // 0..31 : query head
    const int kvh  = h >> 2;          // GQA: kv head
    const int tid  = threadIdx.x;
    const int wv   = tid >> 6;        // wave 0..3
    const int lane = tid & 63;
    const int l15  = lane & 15;
    const int quad = lane >> 4;

    __shared__ bf16_t Ks[64 * 136];       // K tile, row-major [key][d]
    __shared__ bf16_t Vt[128 * 72];       // V^T tile [d][key]
    __shared__ bf16_t Pt[4][32 * 72];     // per-wave P row-major [qrow][key]

    const int qb1  = 2 * sb + 1;              // upper query block of this WG
    const int qb_w = 2 * sb + (wv >> 1);      // this wave's query block
    const int row0 = sb * 128 + wv * 32;      // wave's first global query row

    // ---- Q fragments (B operand of S^T = K*Q^T): qf[qt][kc], loaded once ----
    bf16x8 qf[2][4];
#pragma unroll
    for (int qt = 0; qt < 2; ++qt) {
        const float* qp = Q + (size_t)(row0 + qt * 16 + l15) * 4096 + h * 128;
#pragma unroll
        for (int kc = 0; kc < 4; ++kc) {
            fx4 a = *(const fx4*)(qp + kc * 32 + quad * 8);
            fx4 b = *(const fx4*)(qp + kc * 32 + quad * 8 + 4);
            bf16x8 f;
            f[0] = (bf16_t)a[0]; f[1] = (bf16_t)a[1];
            f[2] = (bf16_t)a[2]; f[3] = (bf16_t)a[3];
            f[4] = (bf16_t)b[0]; f[5] = (bf16_t)b[1];
            f[6] = (bf16_t)b[2]; f[7] = (bf16_t)b[3];
            qf[qt][kc] = f;
        }
    }

    // O^T accumulator: oacc[dt][qt] = O^T[dt*16 + quad*4 + r][qt*16 + l15]
    fx4 oacc[8][2];
    const fx4 zero4 = {0.0f, 0.0f, 0.0f, 0.0f};
#pragma unroll
    for (int dt = 0; dt < 8; ++dt)
#pragma unroll
        for (int qt = 0; qt < 2; ++qt)
            oacc[dt][qt] = zero4;

    float m_st[2] = { -1e30f, -1e30f };
    float l_st[2] = { 0.0f, 0.0f };

    const int colk = tid & 31;    // K staging: float4 column
    const int rowk = tid >> 5;    // K staging: row within 8-row group
    const int dcol = tid & 127;   // V staging: d index
    const int tg   = tid >> 7;    // V staging: key-group parity

    for (int kb = 0; kb <= qb1; ++kb) {
        const bool strided = ((kb + h + 1) & 7) == 0;
        if (!((qb1 - kb < 17) || strided)) continue;   // union over both qbs (uniform)

        // ---------------- stage K tile [64][128] -> Ks ----------------
        {
            const float* kp = K + (size_t)(kb * 64) * 1024 + kvh * 128;
#pragma unroll
            for (int p = 0; p < 8; ++p) {
                const int row = p * 8 + rowk;
                fx4 x = *(const fx4*)(kp + row * 1024 + colk * 4);
                bf16x4 f = { (bf16_t)x[0], (bf16_t)x[1], (bf16_t)x[2], (bf16_t)x[3] };
                *(bf16x4*)&Ks[row * 136 + colk * 4] = f;
            }
            // ------------- stage V^T [128][64] -> Vt -------------
            const float* vp = V + (size_t)(kb * 64) * 1024 + kvh * 128 + dcol;
#pragma unroll
            for (int kk = 0; kk < 8; ++kk) {
                const int k0 = (kk * 2 + tg) * 4;
                float v0 = vp[(size_t)(k0 + 0) * 1024];
                float v1 = vp[(size_t)(k0 + 1) * 1024];
                float v2 = vp[(size_t)(k0 + 2) * 1024];
                float v3 = vp[(size_t)(k0 + 3) * 1024];
                bf16x4 f = { (bf16_t)v0, (bf16_t)v1, (bf16_t)v2, (bf16_t)v3 };
                *(bf16x4*)&Vt[dcol * 72 + k0] = f;
            }
        }
        __syncthreads();

        const bool active = (kb <= qb_w) && ((qb_w - kb < 16) || strided);
        if (active) {
            // ---- S^T = K * Q^T : sacc[kt][qt][r] = S[qt*16+l15][kt*16+quad*4+r]
            fx4 sacc[4][2];
#pragma unroll
            for (int kt = 0; kt < 4; ++kt)
#pragma unroll
                for (int qt = 0; qt < 2; ++qt)
                    sacc[kt][qt] = zero4;

#pragma unroll
            for (int kc = 0; kc < 4; ++kc)
#pragma unroll
                for (int kt = 0; kt < 4; ++kt) {
                    bf16x8 kf = *(const bf16x8*)&Ks[(kt * 16 + l15) * 136 + kc * 32 + quad * 8];
#pragma unroll
                    for (int qt = 0; qt < 2; ++qt)
                        sacc[kt][qt] = __builtin_amdgcn_mfma_f32_16x16x32_bf16(
                            kf, qf[qt][kc], sacc[kt][qt], 0, 0, 0);
                }

            // ---- scale + causal mask on the diagonal block ----
            const bool diag = (kb == qb_w);
            const int qrow_in0 = (wv & 1) * 32 + l15;      // row-in-block, qt=0
#pragma unroll
            for (int kt = 0; kt < 4; ++kt)
#pragma unroll
                for (int qt = 0; qt < 2; ++qt)
#pragma unroll
                    for (int r = 0; r < 4; ++r) {
                        float x = sacc[kt][qt][r] * SCALE_F;
                        const int k_in = kt * 16 + quad * 4 + r;
                        const int q_in = qrow_in0 + qt * 16;
                        if (diag && (q_in < k_in)) x = -1e30f;
                        sacc[kt][qt][r] = x;
                    }

            // ---- online softmax (per qt: one scalar m/l per lane) ----
#pragma unroll
            for (int qt = 0; qt < 2; ++qt) {
                float mx = sacc[0][qt][0];
#pragma unroll
                for (int kt = 0; kt < 4; ++kt)
#pragma unroll
                    for (int r = 0; r < 4; ++r)
                        mx = fmaxf(mx, sacc[kt][qt][r]);
                mx = fmaxf(mx, __shfl_xor(mx, 16));
                mx = fmaxf(mx, __shfl_xor(mx, 32));
                const float mn    = fmaxf(m_st[qt], mx);
                const float alpha = exp2f((m_st[qt] - mn) * LOG2E_F);
                m_st[qt] = mn;
                float rs = 0.0f;
#pragma unroll
                for (int kt = 0; kt < 4; ++kt)
#pragma unroll
                    for (int r = 0; r < 4; ++r) {
                        const float p = exp2f((sacc[kt][qt][r] - mn) * LOG2E_F);
                        sacc[kt][qt][r] = p;
                        rs += p;
                    }
                rs += __shfl_xor(rs, 16);
                rs += __shfl_xor(rs, 32);
                l_st[qt] = l_st[qt] * alpha + rs;
#pragma unroll
                for (int dt = 0; dt < 8; ++dt)
                    oacc[dt][qt] = oacc[dt][qt] * alpha;
            }

            // ---- P -> LDS (row-major [qrow][key], packed b64 writes) ----
#pragma unroll
            for (int qt = 0; qt < 2; ++qt)
#pragma unroll
                for (int kt = 0; kt < 4; ++kt) {
                    bf16x4 f = { (bf16_t)sacc[kt][qt][0], (bf16_t)sacc[kt][qt][1],
                                 (bf16_t)sacc[kt][qt][2], (bf16_t)sacc[kt][qt][3] };
                    *(bf16x4*)&Pt[wv][(qt * 16 + l15) * 72 + kt * 16 + quad * 4] = f;
                }
            // wave-local LDS RAW: drain before cross-lane re-read (no barrier
            // needed — Pt region is wave-private)
            __asm__ __volatile__("s_waitcnt lgkmcnt(0)" ::: "memory");

            bf16x8 pf[2][2];
#pragma unroll
            for (int qt = 0; qt < 2; ++qt)
#pragma unroll
                for (int kc = 0; kc < 2; ++kc)
                    pf[qt][kc] = *(const bf16x8*)&Pt[wv][(qt * 16 + l15) * 72 + kc * 32 + quad * 8];

            // ---- O^T += V^T * P^T ----
#pragma unroll
            for (int kc = 0; kc < 2; ++kc)
#pragma unroll
                for (int dt = 0; dt < 8; ++dt) {
                    bf16x8 vf = *(const bf16x8*)&Vt[(dt * 16 + l15) * 72 + kc * 32 + quad * 8];
#pragma unroll
                    for (int qt = 0; qt < 2; ++qt)
                        oacc[dt][qt] = __builtin_amdgcn_mfma_f32_16x16x32_bf16(
                            vf, pf[qt][kc], oacc[dt][qt], 0, 0, 0);
                }
        }
        __syncthreads();   // protect Ks/Vt before next stage
    }

    // ---- epilogue: O = O^T normalized, float4 stores ----
    const float inv0 = 1.0f / l_st[0];
    const float inv1 = 1.0f / l_st[1];
#pragma unroll
    for (int dt = 0; dt < 8; ++dt)
#pragma unroll
        for (int qt = 0; qt < 2; ++qt) {
            const float inv = qt ? inv1 : inv0;
            fx4 o = oacc[dt][qt] * inv;
            *(fx4*)(O + (size_t)(row0 + qt * 16 + l15) * 4096 + h * 128 + dt * 16 + quad * 4) = o;
        }
}

extern "C" void kernel_launch(void* const* d_in, const int* in_sizes, int n_in,
                              void* d_out, int out_size, void* d_ws, size_t ws_size,
                              hipStream_t stream) {
    (void)in_sizes; (void)n_in; (void)d_ws; (void)ws_size; (void)out_size;
    const float* q = (const float*)d_in[0];
    const float* k = (const float*)d_in[1];
    const float* v = (const float*)d_in[2];
    float* o = (float*)d_out;
    dim3 grid(16, 32);   // 16 query superblocks x 32 heads = 512 WGs (2/CU)
    bsfa_kernel<<<grid, dim3(256), 0, stream>>>(q, k, v, o);
}

// Round 2
// 165.085 us; speedup vs baseline: 1.5217x; 1.5217x over previous
//
#include <hip/hip_runtime.h>

// BlockSparseFlashAttention — Phi-3-small blocksparse prefill, MI355X (gfx950)
// S=2048, H=32, HKV=8 (GQA x4), D=128, BLK=64, LOCAL=16, VERT=8, HEAD_SLIDE=1
//
// R2: latency/balance restructure (R1 was 152us @ 15% occupancy, all pipes idle)
//  - Grid 1024 WGs = (32 qb x 32 heads), 128 thr / 2 waves / 64 q-rows.
//    Wave owns 32 rows (2 qt) -> K/V frag reads amortized x2 across MFMAs.
//  - qb DESCENDING dispatch: heavy WGs first (LPT), light ones backfill.
//  - P region OVERLAYS the K region (P only live after QK consumes Ks; one
//    extra barrier) -> LDS 35 KB -> 4 WGs/CU = 16 waves/CU capacity.
//  - No union waste: all waves share one qb; every staged block is computed.
//  - exp2-domain softmax with SCALE*log2(e) folded into the score.

typedef __bf16 bf16_t;
typedef __bf16 bf16x4 __attribute__((ext_vector_type(4)));
typedef __bf16 bf16x8 __attribute__((ext_vector_type(8)));
typedef float  fx4    __attribute__((ext_vector_type(4)));

#define SL2E_F 0.1275240614354876f   // (1/sqrt(128)) * log2(e)

__launch_bounds__(128, 2)   // 2 waves/EU -> 4 WGs/CU (128-thr blocks)
__global__ void bsfa_kernel(const float* __restrict__ Q,
                            const float* __restrict__ K,
                            const float* __restrict__ V,
                            float* __restrict__ O)
{
    const int x    = blockIdx.x;
    const int qb   = 31 - (x >> 5);   // heavy query blocks dispatched first
    const int h    = x & 31;
    const int kvh  = h >> 2;
    const int tid  = threadIdx.x;     // 0..127
    const int wv   = tid >> 6;        // wave 0..1
    const int lane = tid & 63;
    const int l15  = lane & 15;
    const int quad = lane >> 4;

    __shared__ bf16_t KsPt[64 * 136];   // K tile [key][d]  OR  P (overlay)
    __shared__ bf16_t Vt[128 * 72];     // V^T tile [d][key]

    bf16_t* Pt = &KsPt[wv * (32 * 72)]; // per-wave P [qrow][key], 4608 elts total

    const int row0 = qb * 64 + wv * 32;   // wave's first global query row

    // ---- Q fragments (B operand of S^T = K*Q^T): qf[qt][kc], loaded once ----
    bf16x8 qf[2][4];
#pragma unroll
    for (int qt = 0; qt < 2; ++qt) {
        const float* qp = Q + (size_t)(row0 + qt * 16 + l15) * 4096 + h * 128;
#pragma unroll
        for (int kc = 0; kc < 4; ++kc) {
            fx4 a = *(const fx4*)(qp + kc * 32 + quad * 8);
            fx4 b = *(const fx4*)(qp + kc * 32 + quad * 8 + 4);
            bf16x8 f;
            f[0] = (bf16_t)a[0]; f[1] = (bf16_t)a[1];
            f[2] = (bf16_t)a[2]; f[3] = (bf16_t)a[3];
            f[4] = (bf16_t)b[0]; f[5] = (bf16_t)b[1];
            f[6] = (bf16_t)b[2]; f[7] = (bf16_t)b[3];
            qf[qt][kc] = f;
        }
    }

    // O^T accumulator: oacc[dt][qt] = O^T[dt*16 + quad*4 + r][qt*16 + l15]
    fx4 oacc[8][2];
    const fx4 zero4 = {0.0f, 0.0f, 0.0f, 0.0f};
#pragma unroll
    for (int dt = 0; dt < 8; ++dt)
#pragma unroll
        for (int qt = 0; qt < 2; ++qt)
            oacc[dt][qt] = zero4;

    float m_st[2] = { -1e30f, -1e30f };
    float l_st[2] = { 0.0f, 0.0f };

    const int colk = tid & 31;    // K staging: float4 column
    const int rowk = tid >> 5;    // K staging: row within 4-row group

    for (int kb = 0; kb <= qb; ++kb) {
        if (!((qb - kb < 16) || (((kb + h + 1) & 7) == 0))) continue;  // uniform

        // ---------------- stage K tile [64][128] -> KsPt ----------------
        {
            const float* kp = K + (size_t)(kb * 64) * 1024 + kvh * 128;
#pragma unroll
            for (int p = 0; p < 16; ++p) {
                const int row = p * 4 + rowk;
                fx4 xx = *(const fx4*)(kp + (size_t)row * 1024 + colk * 4);
                bf16x4 f = { (bf16_t)xx[0], (bf16_t)xx[1], (bf16_t)xx[2], (bf16_t)xx[3] };
                *(bf16x4*)&KsPt[row * 136 + colk * 4] = f;
            }
            // ------------- stage V^T [128][64] -> Vt (d = tid) -------------
            const float* vp = V + (size_t)(kb * 64) * 1024 + kvh * 128 + tid;
#pragma unroll
            for (int kk = 0; kk < 16; ++kk) {
                const int k0 = kk * 4;
                float v0 = vp[(size_t)(k0 + 0) * 1024];
                float v1 = vp[(size_t)(k0 + 1) * 1024];
                float v2 = vp[(size_t)(k0 + 2) * 1024];
                float v3 = vp[(size_t)(k0 + 3) * 1024];
                bf16x4 f = { (bf16_t)v0, (bf16_t)v1, (bf16_t)v2, (bf16_t)v3 };
                *(bf16x4*)&Vt[tid * 72 + k0] = f;
            }
        }
        __syncthreads();   // barrier 1: tiles visible

        // ---- S^T = K * Q^T : sacc[kt][qt][r] = S[qt*16+l15][kt*16+quad*4+r]
        fx4 sacc[4][2];
#pragma unroll
        for (int kt = 0; kt < 4; ++kt)
#pragma unroll
            for (int qt = 0; qt < 2; ++qt)
                sacc[kt][qt] = zero4;

#pragma unroll
        for (int kc = 0; kc < 4; ++kc)
#pragma unroll
            for (int kt = 0; kt < 4; ++kt) {
                bf16x8 kf = *(const bf16x8*)&KsPt[(kt * 16 + l15) * 136 + kc * 32 + quad * 8];
#pragma unroll
                for (int qt = 0; qt < 2; ++qt)
                    sacc[kt][qt] = __builtin_amdgcn_mfma_f32_16x16x32_bf16(
                        kf, qf[qt][kc], sacc[kt][qt], 0, 0, 0);
            }

        // ---- scale(log2-domain) + causal mask on the diagonal block ----
        const bool diag = (kb == qb);
        const int qrow_in0 = wv * 32 + l15;      // row-in-block for qt=0
#pragma unroll
        for (int kt = 0; kt < 4; ++kt)
#pragma unroll
            for (int qt = 0; qt < 2; ++qt)
#pragma unroll
                for (int r = 0; r < 4; ++r) {
                    float t = sacc[kt][qt][r] * SL2E_F;
                    const int k_in = kt * 16 + quad * 4 + r;
                    const int q_in = qrow_in0 + qt * 16;
                    if (diag && (q_in < k_in)) t = -1e30f;
                    sacc[kt][qt][r] = t;
                }

        // ---- online softmax (per qt: one scalar m/l per lane) ----
#pragma unroll
        for (int qt = 0; qt < 2; ++qt) {
            float mx = sacc[0][qt][0];
#pragma unroll
            for (int kt = 0; kt < 4; ++kt)
#pragma unroll
                for (int r = 0; r < 4; ++r)
                    mx = fmaxf(mx, sacc[kt][qt][r]);
            mx = fmaxf(mx, __shfl_xor(mx, 16));
            mx = fmaxf(mx, __shfl_xor(mx, 32));
            const float mn    = fmaxf(m_st[qt], mx);
            const float alpha = exp2f(m_st[qt] - mn);
            m_st[qt] = mn;
            float rs = 0.0f;
#pragma unroll
            for (int kt = 0; kt < 4; ++kt)
#pragma unroll
                for (int r = 0; r < 4; ++r) {
                    const float p = exp2f(sacc[kt][qt][r] - mn);
                    sacc[kt][qt][r] = p;
                    rs += p;
                }
            rs += __shfl_xor(rs, 16);
            rs += __shfl_xor(rs, 32);
            l_st[qt] = l_st[qt] * alpha + rs;
#pragma unroll
            for (int dt = 0; dt < 8; ++dt)
                oacc[dt][qt] = oacc[dt][qt] * alpha;
        }

        __syncthreads();   // barrier 2: all Ks reads done before P overlays it

        // ---- P -> LDS (overlay region, row-major [qrow][key], b64 writes) ----
#pragma unroll
        for (int qt = 0; qt < 2; ++qt)
#pragma unroll
            for (int kt = 0; kt < 4; ++kt) {
                bf16x4 f = { (bf16_t)sacc[kt][qt][0], (bf16_t)sacc[kt][qt][1],
                             (bf16_t)sacc[kt][qt][2], (bf16_t)sacc[kt][qt][3] };
                *(bf16x4*)&Pt[(qt * 16 + l15) * 72 + kt * 16 + quad * 4] = f;
            }
        // wave-local LDS RAW drain (Pt region is wave-private; no barrier)
        __asm__ __volatile__("s_waitcnt lgkmcnt(0)" ::: "memory");

        bf16x8 pf[2][2];
#pragma unroll
        for (int qt = 0; qt < 2; ++qt)
#pragma unroll
            for (int kc = 0; kc < 2; ++kc)
                pf[qt][kc] = *(const bf16x8*)&Pt[(qt * 16 + l15) * 72 + kc * 32 + quad * 8];

        // ---- O^T += V^T * P^T ----
#pragma unroll
        for (int kc = 0; kc < 2; ++kc)
#pragma unroll
            for (int dt = 0; dt < 8; ++dt) {
                bf16x8 vf = *(const bf16x8*)&Vt[(dt * 16 + l15) * 72 + kc * 32 + quad * 8];
#pragma unroll
                for (int qt = 0; qt < 2; ++qt)
                    oacc[dt][qt] = __builtin_amdgcn_mfma_f32_16x16x32_bf16(
                        vf, pf[qt][kc], oacc[dt][qt], 0, 0, 0);
            }

        __syncthreads();   // barrier 3: protect KsPt/Vt before next staging
    }

    // ---- epilogue: O = O^T normalized, float4 stores ----
    const float inv0 = 1.0f / l_st[0];
    const float inv1 = 1.0f / l_st[1];
#pragma unroll
    for (int dt = 0; dt < 8; ++dt)
#pragma unroll
        for (int qt = 0; qt < 2; ++qt) {
            const float inv = qt ? inv1 : inv0;
            fx4 o = oacc[dt][qt] * inv;
            *(fx4*)(O + (size_t)(row0 + qt * 16 + l15) * 4096 + h * 128 + dt * 16 + quad * 4) = o;
        }
}

extern "C" void kernel_launch(void* const* d_in, const int* in_sizes, int n_in,
                              void* d_out, int out_size, void* d_ws, size_t ws_size,
                              hipStream_t stream) {
    (void)in_sizes; (void)n_in; (void)d_ws; (void)ws_size; (void)out_size;
    const float* q = (const float*)d_in[0];
    const float* k = (const float*)d_in[1];
    const float* v = (const float*)d_in[2];
    float* o = (float*)d_out;
    bsfa_kernel<<<dim3(1024), dim3(128), 0, stream>>>(q, k, v, o);
}